// Round 15
// baseline (213.517 us; speedup 1.0000x reference)
//
#include <hip/hip_runtime.h>

typedef float f32x4 __attribute__((ext_vector_type(4)));
typedef unsigned long long ull;

#define OFF_PRED 26214400      // 32*128*128*50
#define OFF_XU   56934400      // OFF_PRED + 32*64*300*50
#define NBP 8                  // bp per persistent block; grid = 2048/8 = 256 = 1/CU
#define LROW 328               // LDS row stride bytes (fp8): 320 + 8 pad
#define BUFSZ (64 * LROW)      // 20992 B per buffer

// pack 4 floats into 4 fp8 e4m3 bytes (one u32)
__device__ inline unsigned pack4_fp8(float a, float b, float c, float d) {
    int r = __builtin_amdgcn_cvt_pk_fp8_f32(a, b, 0, false);   // bytes 0,1
    r = __builtin_amdgcn_cvt_pk_fp8_f32(c, d, r, true);        // bytes 2,3
    return (unsigned)r;
}

// ---- K0: build M in MFMA-fragment order, fp8 (unchanged from R14).
// Logical M[640][320]: rows 0..255 = C, 256..555 = A, rest 0; cols k<300 real, else 0.
__global__ void build_M(const float* __restrict__ A, const float* __restrict__ C,
                        unsigned* __restrict__ M) {
    int idx = blockIdx.x * 256 + threadIdx.x;      // u32 index (4 fp8 elems)
    if (idx >= 51200) return;                      // 640*320/4
    int d = idx * 4;
    int e0 = d & 7, lane = (d >> 3) & 63, fs = d >> 9;
    int mt = fs / 10, ks = fs % 10;
    int m = mt * 16 + (lane & 15);
    int k = ks * 32 + (lane >> 4) * 8 + e0;
    float f0 = 0.f, f1 = 0.f, f2 = 0.f, f3 = 0.f;
    const float* src = nullptr;
    if (m < 256) src = C + m * 300;
    else if (m < 556) src = A + (m - 256) * 300;
    if (src) {
        if (k + 0 < 300) f0 = src[k + 0];
        if (k + 1 < 300) f1 = src[k + 1];
        if (k + 2 < 300) f2 = src[k + 2];
        if (k + 3 < 300) f3 = src[k + 3];
    }
    M[idx] = pack4_fp8(f0, f1, f2, f3);
}

// ---- K1: persistent block (1/CU), M register-resident (R14) + double-buffered
//      LDS X-tile with split-batch staging pipelined across the K-loop.
//      Per it: loadA(bp+1) -> compute(buf cur) -> writeA(other)+loadB -> epilogue
//              -> writeB(other) -> ONE barrier.
__global__ __launch_bounds__(512, 2) void gemm_main(
    const float* __restrict__ X, const float* __restrict__ x0,
    const char* __restrict__ M, float* __restrict__ out)
{
    __shared__ char ldsb[2 * BUFSZ];               // 41984 B
    const int tid = threadIdx.x;
    const int wave = tid >> 6, lane = tid & 63;
    const int lr = lane & 15, lg = lane >> 4;
    const int g = wave;
    const int bp0 = blockIdx.x * NBP;

    // staging coords: item i = tid + u*512 -> (t = i%50, jq = i/50), j = jq*4
    int offg[8], offl[8];
    #pragma unroll
    for (int u = 0; u < 8; u++) {
        int i = tid + u * 512;
        int t = i % 50, jq = i / 50;
        offg[u] = jq * 200 + t;                    // float idx into X_bp
        offl[u] = (t + 1) * LROW + jq * 4;         // byte idx into LDS buffer
    }
    const bool v7 = tid < 166;                     // 3750 - 7*512

    // zero-fill both buffers (pad cols & rows 51..63 stay zero across bp's)
    #pragma unroll
    for (int u = 0; u < 11; u++) {
        int i = tid + u * 512;
        if (i < 2 * BUFSZ / 8) ((ull*)ldsb)[i] = 0ULL;
    }

    // ---- register-resident M: wave g -> frags (mt = g*5+j, ks), 8B/lane ----
    long long mf[5][10];
    #pragma unroll
    for (int j = 0; j < 5; j++)
        #pragma unroll
        for (int ks = 0; ks < 10; ks++)
            mf[j][ks] = *(const long long*)(M + (((g * 5 + j) * 10 + ks) * 64 + lane) * 8);

    float sxa[4][4], sxb[4][4], s0x[4];

#define LOAD_A(bp_) { const float* Xb_ = X + (bp_) * 15000;                          \
    _Pragma("unroll")                                                                 \
    for (int u = 0; u < 4; u++) {                                                     \
        const float* s_ = Xb_ + offg[u];                                              \
        sxa[u][0] = s_[0]; sxa[u][1] = s_[50]; sxa[u][2] = s_[100]; sxa[u][3] = s_[150]; \
    }                                                                                 \
    if (tid < 75) { f32x4 v_ = *(const f32x4*)(x0 + (bp_) * 300 + tid * 4);           \
        s0x[0] = v_.x; s0x[1] = v_.y; s0x[2] = v_.z; s0x[3] = v_.w; } }

#define LOAD_B(bp_) { const float* Xb_ = X + (bp_) * 15000;                          \
    _Pragma("unroll")                                                                 \
    for (int u = 4; u < 8; u++) if (u < 7 || v7) {                                    \
        const float* s_ = Xb_ + offg[u];                                              \
        sxb[u-4][0] = s_[0]; sxb[u-4][1] = s_[50]; sxb[u-4][2] = s_[100]; sxb[u-4][3] = s_[150]; \
    } }

#define WRITE_A(wb_) {                                                                \
    _Pragma("unroll")                                                                 \
    for (int u = 0; u < 4; u++)                                                       \
        *(unsigned*)((wb_) + offl[u]) = pack4_fp8(sxa[u][0], sxa[u][1], sxa[u][2], sxa[u][3]); \
    if (tid < 75) *(unsigned*)((wb_) + tid * 4) = pack4_fp8(s0x[0], s0x[1], s0x[2], s0x[3]); }

#define WRITE_B(wb_) {                                                                \
    _Pragma("unroll")                                                                 \
    for (int u = 4; u < 8; u++) if (u < 7 || v7)                                      \
        *(unsigned*)((wb_) + offl[u]) = pack4_fp8(sxb[u-4][0], sxb[u-4][1], sxb[u-4][2], sxb[u-4][3]); }

    // prologue: stage bp0 fully into buf0
    LOAD_A(bp0); LOAD_B(bp0);
    WRITE_A(ldsb); WRITE_B(ldsb);
    __syncthreads();

    #pragma unroll 1
    for (int it = 0; it < NBP; ++it) {
        const int bp = bp0 + it;
        const int b = bp >> 6, p = bp & 63;
        char* rb = ldsb + (it & 1) * BUFSZ;
        char* wb = ldsb + ((it & 1) ^ 1) * BUFSZ;

        // issue first half of next bp's loads; latency hides under the K-loop
        if (it + 1 < NBP) LOAD_A(bp + 1);

        // ---- compute: zero VMEM K-loop ----
        f32x4 acc[5][4];
        #pragma unroll
        for (int j = 0; j < 5; j++)
            #pragma unroll
            for (int nt = 0; nt < 4; nt++)
                acc[j][nt] = (f32x4){0.f, 0.f, 0.f, 0.f};

        #pragma unroll
        for (int ks = 0; ks < 10; ks++) {
            long long a0 = *(const long long*)(rb + (0 * 16 + lr) * LROW + ks * 32 + lg * 8);
            long long a1 = *(const long long*)(rb + (1 * 16 + lr) * LROW + ks * 32 + lg * 8);
            long long a2 = *(const long long*)(rb + (2 * 16 + lr) * LROW + ks * 32 + lg * 8);
            long long a3 = *(const long long*)(rb + (3 * 16 + lr) * LROW + ks * 32 + lg * 8);
            #pragma unroll
            for (int j = 0; j < 5; j++) {
                acc[j][0] = __builtin_amdgcn_mfma_f32_16x16x32_fp8_fp8(a0, mf[j][ks], acc[j][0], 0, 0, 0);
                acc[j][1] = __builtin_amdgcn_mfma_f32_16x16x32_fp8_fp8(a1, mf[j][ks], acc[j][1], 0, 0, 0);
                acc[j][2] = __builtin_amdgcn_mfma_f32_16x16x32_fp8_fp8(a2, mf[j][ks], acc[j][2], 0, 0, 0);
                acc[j][3] = __builtin_amdgcn_mfma_f32_16x16x32_fp8_fp8(a3, mf[j][ks], acc[j][3], 0, 0, 0);
            }
        }

        // drain half A into the other buffer, then issue half B's loads
        if (it + 1 < NBP) { WRITE_A(wb); LOAD_B(bp + 1); }

        // ---- epilogue: col m = g*80 + j*16 + lr, ext-col n = nt*16 + lg*4 + q ----
        {
            const int gr = p >> 3, gc = p & 7;
            #pragma unroll
            for (int j = 0; j < 5; j++) {
                int colm = g * 80 + j * 16 + lr;
                if (colm < 256) {
                    // recon row d -> vid[b][gr*16 + d/16][gc*16 + d%16][t], t = n-1
                    int base = b * 819200 + ((gr * 16 + (colm >> 4)) * 128 + gc * 16 + (colm & 15)) * 50;
                    #pragma unroll
                    for (int nt = 0; nt < 4; nt++) {
                        int t0 = nt * 16 + lg * 4;
                        if (t0 == 0) {
                            out[base + 0] = acc[j][0][1];
                            out[base + 1] = acc[j][0][2];
                            out[base + 2] = acc[j][0][3];
                        } else if (t0 <= 46) {
                            f32x4 v = acc[j][nt];
                            __builtin_memcpy(&out[base + t0 - 1], &v, 16);
                        } else if (t0 == 48) {
                            out[base + 47] = acc[j][nt][0];
                            out[base + 48] = acc[j][nt][1];
                            out[base + 49] = acc[j][nt][2];
                        }
                    }
                } else if (colm < 556) {
                    // X_pred row i = colm-256, t = n
                    int base = OFF_PRED + (bp * 300 + (colm - 256)) * 50;
                    #pragma unroll
                    for (int nt = 0; nt < 4; nt++) {
                        int t0 = nt * 16 + lg * 4;
                        if (t0 <= 46) {
                            f32x4 v = acc[j][nt];
                            __builtin_memcpy(&out[base + t0], &v, 16);
                        } else if (t0 == 48) {
                            out[base + 48] = acc[j][nt][0];
                            out[base + 49] = acc[j][nt][1];
                        }
                    }
                }
            }
        }

        // drain half B, single barrier, swap buffers
        if (it + 1 < NBP) WRITE_B(wb);
        __syncthreads();
    }
}

// ---- K2: X_U[b,i,t] = 0.5*(1+exp(-(B·U)[b,i,t])) * sum_p |X[b,p,i,t]|
__global__ void xu_kernel(const float* __restrict__ X, const float* __restrict__ U,
                          const float* __restrict__ B, float* __restrict__ out) {
    int id = blockIdx.x * 256 + threadIdx.x;
    if (id >= 480000) return;
    int t = id % 50;
    int i = (id / 50) % 300;
    int b = id / 15000;
    const float* xp = X + b * 960000 + i * 50 + t;
    float s = 0.f;
    #pragma unroll 8
    for (int pp = 0; pp < 64; pp++) s += fabsf(xp[pp * 15000]);
    float bu = 0.f;
    const float* up = U + b * 2000 + t;
    const float* Bp = B + i * 40;
    #pragma unroll 8
    for (int q = 0; q < 40; q++) bu += Bp[q] * up[q * 50];
    out[OFF_XU + id] = 0.5f * (1.f + expf(-bu)) * s;
}

extern "C" void kernel_launch(void* const* d_in, const int* in_sizes, int n_in,
                              void* d_out, int out_size, void* d_ws, size_t ws_size,
                              hipStream_t stream) {
    const float* X  = (const float*)d_in[0];
    const float* U  = (const float*)d_in[1];
    const float* x0 = (const float*)d_in[2];
    const float* A  = (const float*)d_in[3];
    const float* B  = (const float*)d_in[4];
    const float* C  = (const float*)d_in[5];
    float* out = (float*)d_out;
    unsigned* M = (unsigned*)d_ws;      // 640*320 fp8 = 204,800 B (fragment-ordered)

    build_M<<<200, 256, 0, stream>>>(A, C, M);
    gemm_main<<<256, 512, 0, stream>>>(X, x0, (const char*)M, out);
    xu_kernel<<<1875, 256, 0, stream>>>(X, U, B, out);
}